// Round 8
// baseline (314.353 us; speedup 1.0000x reference)
//
#include <hip/hip_runtime.h>
#include <math.h>

#define FDIM 128
#define NEG_SLOPE 0.2f

__device__ __forceinline__ float lrelu(float x) {
    return x > 0.f ? x : NEG_SLOPE * x;
}

// bf16 helpers (RNE; inputs finite)
__device__ __forceinline__ unsigned short f2bf(float f) {
    unsigned u = __float_as_uint(f);
    return (unsigned short)((u + 0x7FFFu + ((u >> 16) & 1u)) >> 16);
}
__device__ __forceinline__ float bf2f(unsigned short h) {
    return __uint_as_float((unsigned)h << 16);
}

// ---------------- rank: rank[e] = atomicAdd(&cnt[dst*stride],1) ----------------
// 4 edges/thread (4 independent atomics in flight); counters padded to one per
// 128B line (stride=32) to kill cache-line convoying. NO big LDS here —
// full occupancy for atomic concurrency (R7 lesson).

__global__ __launch_bounds__(256) void k_rank(const int* __restrict__ dstp,
                                              int E, int N,
                                              int* __restrict__ cnt, int stride,
                                              unsigned short* __restrict__ rank) {
    int total = E + N;
    int e0 = (blockIdx.x * 256 + threadIdx.x) * 4;
    if (e0 >= total) return;
    if (e0 + 3 < E) {
        int4 d4 = *(const int4*)(dstp + e0);
        ushort4 r;
        r.x = (unsigned short)atomicAdd(&cnt[d4.x * stride], 1);
        r.y = (unsigned short)atomicAdd(&cnt[d4.y * stride], 1);
        r.z = (unsigned short)atomicAdd(&cnt[d4.z * stride], 1);
        r.w = (unsigned short)atomicAdd(&cnt[d4.w * stride], 1);
        *(ushort4*)(rank + e0) = r;
    } else {
#pragma unroll
        for (int q = 0; q < 4; ++q) {
            int e = e0 + q;
            if (e < total) {
                int d = (e < E) ? dstp[e] : (e - E);
                rank[e] = (unsigned short)atomicAdd(&cnt[d * stride], 1);
            }
        }
    }
}

// ---------------- GEMM (+ fused attention scalars): 64 rows/block ----------------

__global__ __launch_bounds__(256) void k_gemm(const float* __restrict__ A,
                                              const float* __restrict__ W,
                                              unsigned short* __restrict__ out,
                                              const float* __restrict__ att_s,
                                              const float* __restrict__ att_d,
                                              float* __restrict__ asrc,
                                              float* __restrict__ adst, int nrows) {
    __shared__ float Ws[FDIM * FDIM];
    __shared__ float sAs[FDIM], sAd[FDIM];
    int t = threadIdx.x;
    for (int f = t; f < FDIM * FDIM / 4; f += 256)
        ((float4*)Ws)[f] = ((const float4*)W)[f];
    if (t < FDIM) { sAs[t] = att_s[t]; sAd[t] = att_d[t]; }
    __syncthreads();

    int tx = t & 31;
    int ty = t >> 5;
    int row0 = blockIdx.x * 64 + ty * 8;

    float acc[8][4];
#pragma unroll
    for (int i = 0; i < 8; ++i)
#pragma unroll
        for (int j = 0; j < 4; ++j) acc[i][j] = 0.f;

    int rr[8];
#pragma unroll
    for (int i = 0; i < 8; ++i)
        rr[i] = (row0 + i < nrows) ? (row0 + i) : (nrows - 1);

#pragma unroll 2
    for (int k4 = 0; k4 < FDIM; k4 += 4) {
        float4 xv[8];
#pragma unroll
        for (int i = 0; i < 8; ++i)
            xv[i] = *(const float4*)(A + (size_t)rr[i] * FDIM + k4);
#pragma unroll
        for (int q = 0; q < 4; ++q) {
            float4 wv = *(float4*)&Ws[(k4 + q) * FDIM + tx * 4];
#pragma unroll
            for (int i = 0; i < 8; ++i) {
                float xs = (q == 0) ? xv[i].x : (q == 1) ? xv[i].y : (q == 2) ? xv[i].z : xv[i].w;
                acc[i][0] = fmaf(xs, wv.x, acc[i][0]);
                acc[i][1] = fmaf(xs, wv.y, acc[i][1]);
                acc[i][2] = fmaf(xs, wv.z, acc[i][2]);
                acc[i][3] = fmaf(xs, wv.w, acc[i][3]);
            }
        }
    }
#pragma unroll
    for (int i = 0; i < 8; ++i) {
        if (row0 + i < nrows) {
            ushort4 o;
            o.x = f2bf(acc[i][0]);
            o.y = f2bf(acc[i][1]);
            o.z = f2bf(acc[i][2]);
            o.w = f2bf(acc[i][3]);
            *(ushort4*)(out + (size_t)(row0 + i) * FDIM + tx * 4) = o;
        }
    }

    float ps[8], pd[8];
#pragma unroll
    for (int i = 0; i < 8; ++i) {
        float s = 0.f, d = 0.f;
#pragma unroll
        for (int j = 0; j < 4; ++j) {
            s = fmaf(acc[i][j], sAs[tx * 4 + j], s);
            d = fmaf(acc[i][j], sAd[tx * 4 + j], d);
        }
        ps[i] = s; pd[i] = d;
    }
#pragma unroll
    for (int off = 8; off; off >>= 1) {
#pragma unroll
        for (int i = 0; i < 8; ++i) {
            ps[i] += __shfl_xor(ps[i], off);
            pd[i] += __shfl_xor(pd[i], off);
        }
    }
    if ((tx & 15) == 0) {
        int head = tx >> 4;
#pragma unroll
        for (int i = 0; i < 8; ++i) {
            if (row0 + i < nrows) {
                asrc[2 * (row0 + i) + head] = ps[i];
                adst[2 * (row0 + i) + head] = pd[i];
            }
        }
    }
}

// ---------------- scan over padded counters ----------------

__global__ __launch_bounds__(256) void k_scan_local(const int* __restrict__ deg,
                                                    int stride,
                                                    int* __restrict__ rowp,
                                                    int* __restrict__ bsum, int n) {
    __shared__ int sh[256];
    int b = blockIdx.x, t = threadIdx.x;
    int base = b * 1024 + t * 4;
    int4 v = make_int4(0, 0, 0, 0);
    if (base < n)     v.x = deg[(size_t)base * stride];
    if (base + 1 < n) v.y = deg[(size_t)(base + 1) * stride];
    if (base + 2 < n) v.z = deg[(size_t)(base + 2) * stride];
    if (base + 3 < n) v.w = deg[(size_t)(base + 3) * stride];
    int s = v.x + v.y + v.z + v.w;
    sh[t] = s;
    __syncthreads();
    for (int off = 1; off < 256; off <<= 1) {
        int u = (t >= off) ? sh[t - off] : 0;
        __syncthreads();
        sh[t] += u;
        __syncthreads();
    }
    int excl = t ? sh[t - 1] : 0;
    int r0 = excl + v.x, r1 = r0 + v.y, r2 = r1 + v.z, r3 = r2 + v.w;
    if (base < n)     rowp[base + 1] = r0;
    if (base + 1 < n) rowp[base + 2] = r1;
    if (base + 2 < n) rowp[base + 3] = r2;
    if (base + 3 < n) rowp[base + 4] = r3;
    if (t == 255) bsum[b] = sh[255];
}

__global__ void k_scan_mid(int* __restrict__ bsum, int nb) {
    int lane = threadIdx.x;
    int own = (lane < nb) ? bsum[lane] : 0;
    int v = own;
    for (int off = 1; off < 64; off <<= 1) {
        int u = __shfl(v, lane - off);
        if (lane >= off) v += u;
    }
    if (lane < nb) bsum[lane] = v - own;  // exclusive
}

__global__ __launch_bounds__(256) void k_scan_add(const int* __restrict__ bsum,
                                                  int* __restrict__ rowp, int n) {
    int idx = blockIdx.x * 256 + threadIdx.x;
    if (idx > n) return;
    if (idx == 0) { rowp[0] = 0; return; }
    int blk = (idx - 1) >> 10;
    if (blk > 0) rowp[idx] += bsum[blk];
}

// ---------------- place (4 edges/thread) ----------------

__global__ __launch_bounds__(256) void k_place(const int* __restrict__ srcp,
                                               const int* __restrict__ dstp,
                                               int E, int N,
                                               const int* __restrict__ rowp,
                                               const unsigned short* __restrict__ rank,
                                               int* __restrict__ col) {
    int total = E + N;
    int e0 = (blockIdx.x * 256 + threadIdx.x) * 4;
    if (e0 >= total) return;
    if (e0 + 3 < E) {
        int4 s4 = *(const int4*)(srcp + e0);
        int4 d4 = *(const int4*)(dstp + e0);
        ushort4 r4 = *(const ushort4*)(rank + e0);
        col[rowp[d4.x] + r4.x] = s4.x;
        col[rowp[d4.y] + r4.y] = s4.y;
        col[rowp[d4.z] + r4.z] = s4.z;
        col[rowp[d4.w] + r4.w] = s4.w;
    } else {
#pragma unroll
        for (int q = 0; q < 4; ++q) {
            int e = e0 + q;
            if (e < total) {
                int s, d;
                if (e < E) { s = srcp[e]; d = dstp[e]; }
                else       { s = d = e - E; }
                col[rowp[d] + rank[e]] = s;
            }
        }
    }
}

// ---------------- per-dst softmax + aggregation: ONE WAVE PER NODE ----------------

__global__ __launch_bounds__(256) void k_aggregate(const unsigned short* __restrict__ h,
                                                   const float* __restrict__ asrc,
                                                   const float* __restrict__ adst,
                                                   const int* __restrict__ rowp,
                                                   const int* __restrict__ col,
                                                   const float* __restrict__ bias,
                                                   float* __restrict__ outbuf,
                                                   const float* __restrict__ fcW,
                                                   const float* __restrict__ fcb,
                                                   float* __restrict__ outfin, int n) {
    __shared__ int   scol[4][64];
    __shared__ float sal0[4][64], sal1[4][64];

    int t = threadIdx.x;
    int w = t >> 6;
    int lane = t & 63;
    int node = blockIdx.x * 4 + w;
    if (node >= n) return;

    int start = rowp[node];
    int deg = rowp[node + 1] - start;
    float2 adv = *(const float2*)(adst + 2 * node);
    float ad0 = adv.x, ad1 = adv.y;
    const ushort2* __restrict__ hb = (const ushort2*)h;
    const float* __restrict__ amy = (lane < 32) ? sal0[w] : sal1[w];

    float m0 = -1e30f, m1 = -1e30f;
    float p0 = 0.f, p1 = 0.f;
    float accx = 0.f, accy = 0.f;

    for (int base = 0; base < deg; base += 64) {
        int cnt = min(64, deg - base);
        float v0 = -1e30f, v1 = -1e30f;
        if (lane < cnt) {
            int s = col[start + base + lane];
            scol[w][lane] = s;
            float2 av = *(const float2*)(asrc + 2 * s);
            v0 = lrelu(av.x + ad0);
            v1 = lrelu(av.y + ad1);
        }
        float c0 = v0, c1 = v1;
#pragma unroll
        for (int off = 32; off; off >>= 1) {
            c0 = fmaxf(c0, __shfl_xor(c0, off));
            c1 = fmaxf(c1, __shfl_xor(c1, off));
        }
        float nm0 = fmaxf(m0, c0), nm1 = fmaxf(m1, c1);
        float r0 = __expf(m0 - nm0), r1 = __expf(m1 - nm1);
        m0 = nm0; m1 = nm1;
        p0 *= r0; p1 *= r1;
        float rmy = (lane < 32) ? r0 : r1;
        accx *= rmy; accy *= rmy;
        float e0 = (lane < cnt) ? __expf(v0 - m0) : 0.f;
        float e1 = (lane < cnt) ? __expf(v1 - m1) : 0.f;
        p0 += e0; p1 += e1;
        sal0[w][lane] = e0;
        sal1[w][lane] = e1;
        float2 g0 = make_float2(0.f, 0.f), g1 = make_float2(0.f, 0.f);
        float2 g2 = make_float2(0.f, 0.f), g3 = make_float2(0.f, 0.f);
        int i = 0;
        for (; i + 3 < cnt; i += 4) {
            unsigned sa = (unsigned)scol[w][i];
            unsigned sb = (unsigned)scol[w][i + 1];
            unsigned sc = (unsigned)scol[w][i + 2];
            unsigned sd = (unsigned)scol[w][i + 3];
            float wa = amy[i], wb = amy[i + 1], wc = amy[i + 2], wd = amy[i + 3];
            ushort2 ha = hb[sa * 64u + lane];
            ushort2 hv = hb[sb * 64u + lane];
            ushort2 hc = hb[sc * 64u + lane];
            ushort2 hd = hb[sd * 64u + lane];
            g0.x = fmaf(bf2f(ha.x), wa, g0.x); g0.y = fmaf(bf2f(ha.y), wa, g0.y);
            g1.x = fmaf(bf2f(hv.x), wb, g1.x); g1.y = fmaf(bf2f(hv.y), wb, g1.y);
            g2.x = fmaf(bf2f(hc.x), wc, g2.x); g2.y = fmaf(bf2f(hc.y), wc, g2.y);
            g3.x = fmaf(bf2f(hd.x), wd, g3.x); g3.y = fmaf(bf2f(hd.y), wd, g3.y);
        }
        for (; i < cnt; ++i) {
            unsigned s = (unsigned)scol[w][i];
            float a = amy[i];
            ushort2 hv = hb[s * 64u + lane];
            g0.x = fmaf(bf2f(hv.x), a, g0.x);
            g0.y = fmaf(bf2f(hv.y), a, g0.y);
        }
        accx += g0.x + g1.x + g2.x + g3.x;
        accy += g0.y + g1.y + g2.y + g3.y;
    }

#pragma unroll
    for (int off = 32; off; off >>= 1) {
        p0 += __shfl_xor(p0, off);
        p1 += __shfl_xor(p1, off);
    }
    float invmy = (lane < 32) ? 1.f / (p0 + 1e-16f) : 1.f / (p1 + 1e-16f);
    accx *= invmy;
    accy *= invmy;

    int c0i = 2 * lane, c1i = 2 * lane + 1;
    float2 bv = *(const float2*)(bias + c0i);
    float o0 = fmaxf(accx + bv.x, 0.f);
    float o1 = fmaxf(accy + bv.y, 0.f);
    if (outbuf)
        *(float2*)(outbuf + (size_t)node * FDIM + c0i) = make_float2(o0, o1);
    if (outfin) {
        float2 fv = *(const float2*)(fcW + c0i);
        float p = fmaf(o0, fv.x, o1 * fv.y);
#pragma unroll
        for (int off = 32; off; off >>= 1) p += __shfl_xor(p, off);
        if (lane == 0) outfin[node] = 1.f / (1.f + __expf(-(p + fcb[0])));
    }
}

// ---------------- host ----------------

static inline size_t rnd256(size_t x) { return (x + 255) & ~(size_t)255; }

extern "C" void kernel_launch(void* const* d_in, const int* in_sizes, int n_in,
                              void* d_out, int out_size, void* d_ws, size_t ws_size,
                              hipStream_t stream) {
    const float* x    = (const float*)d_in[0];
    const int*   ei   = (const int*)d_in[1];
    const float* W1   = (const float*)d_in[3];
    const float* as1  = (const float*)d_in[4];
    const float* ad1  = (const float*)d_in[5];
    const float* b1   = (const float*)d_in[6];
    const float* W2   = (const float*)d_in[7];
    const float* as2  = (const float*)d_in[8];
    const float* ad2  = (const float*)d_in[9];
    const float* b2   = (const float*)d_in[10];
    const float* fcW  = (const float*)d_in[11];
    const float* fcb  = (const float*)d_in[12];

    int N = in_sizes[0] / FDIM;
    int E = in_sizes[2];
    int E2 = E + N;
    const int* srcp = ei;
    const int* dstp = ei + E;

    char* w = (char*)d_ws;
    unsigned short* hbuf = (unsigned short*)w; w += rnd256((size_t)N * FDIM * sizeof(unsigned short));
    float* obuf = (float*)w;  w += rnd256((size_t)N * FDIM * sizeof(float));
    float* asrc = (float*)w;  w += rnd256((size_t)N * 2 * sizeof(float));
    float* adst = (float*)w;  w += rnd256((size_t)N * 2 * sizeof(float));
    int* rowp = (int*)w;      w += rnd256((size_t)(N + 1) * sizeof(int));
    int* bsum = (int*)w;      w += rnd256((size_t)256 * sizeof(int));
    unsigned short* rank = (unsigned short*)w; w += rnd256((size_t)E2 * sizeof(unsigned short));
    int* col  = (int*)w;      w += rnd256((size_t)E2 * sizeof(int));
    // counters last: line-pad as far as the workspace allows (32 ints = 128B line)
    size_t used = (size_t)(w - (char*)d_ws);
    int stride = 32;
    while (stride > 1 && used + (size_t)N * stride * sizeof(int) > ws_size) stride >>= 1;
    int* cnt = (int*)w;

    int ggrid = (N + 63) / 64;
    int rgrid = (E2 + 1023) / 1024;
    int nblk = (N + 1023) / 1024;
    int agrid = (N + 3) / 4;

    hipMemsetAsync(cnt, 0, (size_t)N * stride * sizeof(int), stream);

    // rank (atomic-bound, full occupancy) then layer-1 GEMM (VALU-bound)
    k_rank<<<rgrid, 256, 0, stream>>>(dstp, E, N, cnt, stride, rank);
    k_gemm<<<ggrid, 256, 0, stream>>>(x, W1, hbuf, as1, ad1, asrc, adst, N);

    // scan + place
    k_scan_local<<<nblk, 256, 0, stream>>>(cnt, stride, rowp, bsum, N);
    k_scan_mid<<<1, 64, 0, stream>>>(bsum, nblk);
    k_scan_add<<<(N + 256) / 256, 256, 0, stream>>>(bsum, rowp, N);
    k_place<<<(E2 + 1023) / 1024, 256, 0, stream>>>(srcp, dstp, E, N, rowp, rank, col);

    // layer 1 aggregate
    k_aggregate<<<agrid, 256, 0, stream>>>(hbuf, asrc, adst, rowp, col, b1,
                                           obuf, nullptr, nullptr, nullptr, N);

    // layer 2
    k_gemm<<<ggrid, 256, 0, stream>>>(obuf, W2, hbuf, as2, ad2, asrc, adst, N);
    k_aggregate<<<agrid, 256, 0, stream>>>(hbuf, asrc, adst, rowp, col, b2,
                                           nullptr, fcW, fcb, (float*)d_out, N);
}

// Round 9
// 260.141 us; speedup vs baseline: 1.2084x; 1.2084x over previous
//
#include <hip/hip_runtime.h>
#include <math.h>

#define FDIM 128
#define NEG_SLOPE 0.2f

__device__ __forceinline__ float lrelu(float x) {
    return x > 0.f ? x : NEG_SLOPE * x;
}

// bf16 helpers (RNE; inputs finite)
__device__ __forceinline__ unsigned short f2bf(float f) {
    unsigned u = __float_as_uint(f);
    return (unsigned short)((u + 0x7FFFu + ((u >> 16) & 1u)) >> 16);
}
__device__ __forceinline__ float bf2f(unsigned short h) {
    return __uint_as_float((unsigned)h << 16);
}

// ================= atomic-free radix CSR build =================
// Device atomics cost 32B near-memory RMW each (R8: 54MB WRITE, 800GB/s wall).
// Two-level radix: coarse bucket = dst>>8 (196 buckets), all contention in LDS.

// pass 1: per-block LDS histogram over coarse buckets
__global__ __launch_bounds__(256) void k_hist(const int* __restrict__ dstp,
                                              int E, int N,
                                              int* __restrict__ hist,
                                              int nb1, int nbuck) {
    __shared__ int hl[256];
    int t = threadIdx.x, blk = blockIdx.x;
    hl[t] = 0;
    __syncthreads();
    int total = E + N;
    int e0 = blk * 1024 + t * 4;
    if (e0 < total) {
        if (e0 + 3 < E) {
            int4 d4 = *(const int4*)(dstp + e0);
            atomicAdd(&hl[d4.x >> 8], 1);
            atomicAdd(&hl[d4.y >> 8], 1);
            atomicAdd(&hl[d4.z >> 8], 1);
            atomicAdd(&hl[d4.w >> 8], 1);
        } else {
#pragma unroll
            for (int q = 0; q < 4; ++q) {
                int e = e0 + q;
                if (e < total) {
                    int d = (e < E) ? dstp[e] : (e - E);
                    atomicAdd(&hl[d >> 8], 1);
                }
            }
        }
    }
    __syncthreads();
    if (t < nbuck) hist[t * nb1 + blk] = hl[t];
}

// generic exclusive scan (3 kernels), in-place capable
__global__ __launch_bounds__(256) void k_scan1(const int* __restrict__ in,
                                               int* __restrict__ out,
                                               int* __restrict__ bsum, int M) {
    __shared__ int sh[256];
    int b = blockIdx.x, t = threadIdx.x;
    int base = b * 1024 + t * 4;
    int4 v = make_int4(0, 0, 0, 0);
    if (base + 3 < M) v = *(const int4*)(in + base);
    else {
        if (base < M)     v.x = in[base];
        if (base + 1 < M) v.y = in[base + 1];
        if (base + 2 < M) v.z = in[base + 2];
        if (base + 3 < M) v.w = in[base + 3];
    }
    int s = v.x + v.y + v.z + v.w;
    sh[t] = s;
    __syncthreads();
    for (int off = 1; off < 256; off <<= 1) {
        int u = (t >= off) ? sh[t - off] : 0;
        __syncthreads();
        sh[t] += u;
        __syncthreads();
    }
    int excl = t ? sh[t - 1] : 0;
    if (base < M)     out[base]     = excl;
    if (base + 1 < M) out[base + 1] = excl + v.x;
    if (base + 2 < M) out[base + 2] = excl + v.x + v.y;
    if (base + 3 < M) out[base + 3] = excl + v.x + v.y + v.z;
    if (t == 255) bsum[b] = sh[255];
}

__global__ __launch_bounds__(256) void k_scan2(int* __restrict__ bsum, int nb) {
    __shared__ int sh[256];
    int t = threadIdx.x;
    int chunk = (nb + 255) >> 8;
    int b0 = t * chunk, b1 = min(b0 + chunk, nb);
    int s = 0;
    for (int i = b0; i < b1; ++i) s += bsum[i];
    sh[t] = s;
    __syncthreads();
    for (int off = 1; off < 256; off <<= 1) {
        int u = (t >= off) ? sh[t - off] : 0;
        __syncthreads();
        sh[t] += u;
        __syncthreads();
    }
    int run = t ? sh[t - 1] : 0;
    for (int i = b0; i < b1; ++i) { int v = bsum[i]; bsum[i] = run; run += v; }
}

__global__ __launch_bounds__(256) void k_scan3(int* __restrict__ out,
                                               const int* __restrict__ bsum, int M) {
    int i = blockIdx.x * 256 + threadIdx.x;
    if (i < M) out[i] += bsum[i >> 10];
}

// pass 2: scatter edges into bucket-partitioned part[] (packed (src<<8)|dlocal)
__global__ __launch_bounds__(256) void k_scatter(const int* __restrict__ srcp,
                                                 const int* __restrict__ dstp,
                                                 int E, int N,
                                                 const int* __restrict__ histScan,
                                                 int nb1, int nbuck,
                                                 int* __restrict__ part) {
    __shared__ int baseL[256];
    __shared__ int runL[256];
    int t = threadIdx.x, blk = blockIdx.x;
    if (t < nbuck) baseL[t] = histScan[t * nb1 + blk];
    runL[t] = 0;
    __syncthreads();
    int total = E + N;
    int e0 = blk * 1024 + t * 4;
    if (e0 >= total) return;
    if (e0 + 3 < E) {
        int4 s4 = *(const int4*)(srcp + e0);
        int4 d4 = *(const int4*)(dstp + e0);
        int r, bin;
        bin = d4.x >> 8; r = atomicAdd(&runL[bin], 1);
        part[baseL[bin] + r] = (s4.x << 8) | (d4.x & 255);
        bin = d4.y >> 8; r = atomicAdd(&runL[bin], 1);
        part[baseL[bin] + r] = (s4.y << 8) | (d4.y & 255);
        bin = d4.z >> 8; r = atomicAdd(&runL[bin], 1);
        part[baseL[bin] + r] = (s4.z << 8) | (d4.z & 255);
        bin = d4.w >> 8; r = atomicAdd(&runL[bin], 1);
        part[baseL[bin] + r] = (s4.w << 8) | (d4.w & 255);
    } else {
#pragma unroll
        for (int q = 0; q < 4; ++q) {
            int e = e0 + q;
            if (e < total) {
                int s, d;
                if (e < E) { s = srcp[e]; d = dstp[e]; }
                else       { s = d = e - E; }
                int bin = d >> 8;
                int r = atomicAdd(&runL[bin], 1);
                part[baseL[bin] + r] = (s << 8) | (d & 255);
            }
        }
    }
}

// pass 3: one block per bucket — fine count, LDS scan, rowp + col (LDS-rank place)
__global__ __launch_bounds__(256) void k_bucket(const int* __restrict__ part,
                                                const int* __restrict__ histScan,
                                                int nb1, int nbuck, int E2, int N,
                                                int* __restrict__ rowp,
                                                int* __restrict__ col) {
    __shared__ int cntL[256];
    __shared__ int exclL[256];
    __shared__ int sh[256];
    int b = blockIdx.x, t = threadIdx.x;
    int s0 = histScan[b * nb1];
    int s1 = (b == nbuck - 1) ? E2 : histScan[(b + 1) * nb1];

    cntL[t] = 0;
    __syncthreads();
    for (int i = s0 + t; i < s1; i += 256)
        atomicAdd(&cntL[part[i] & 255], 1);
    __syncthreads();

    // exclusive scan of cntL
    sh[t] = cntL[t];
    __syncthreads();
    for (int off = 1; off < 256; off <<= 1) {
        int u = (t >= off) ? sh[t - off] : 0;
        __syncthreads();
        sh[t] += u;
        __syncthreads();
    }
    exclL[t] = t ? sh[t - 1] : 0;
    __syncthreads();

    int d = b * 256 + t;
    if (d < N) rowp[d] = s0 + exclL[t];
    if (b == nbuck - 1 && t == 0) rowp[N] = E2;

    cntL[t] = 0;
    __syncthreads();
    for (int i = s0 + t; i < s1; i += 256) {
        int p = part[i];
        int dl = p & 255;
        int r = atomicAdd(&cntL[dl], 1);
        col[s0 + exclL[dl] + r] = (int)((unsigned)p >> 8);
    }
}

// ---------------- GEMM (+ fused attention scalars): 64 rows/block ----------------

__global__ __launch_bounds__(256) void k_gemm(const float* __restrict__ A,
                                              const float* __restrict__ W,
                                              unsigned short* __restrict__ out,
                                              const float* __restrict__ att_s,
                                              const float* __restrict__ att_d,
                                              float* __restrict__ asrc,
                                              float* __restrict__ adst, int nrows) {
    __shared__ float Ws[FDIM * FDIM];
    __shared__ float sAs[FDIM], sAd[FDIM];
    int t = threadIdx.x;
    for (int f = t; f < FDIM * FDIM / 4; f += 256)
        ((float4*)Ws)[f] = ((const float4*)W)[f];
    if (t < FDIM) { sAs[t] = att_s[t]; sAd[t] = att_d[t]; }
    __syncthreads();

    int tx = t & 31;
    int ty = t >> 5;
    int row0 = blockIdx.x * 64 + ty * 8;

    float acc[8][4];
#pragma unroll
    for (int i = 0; i < 8; ++i)
#pragma unroll
        for (int j = 0; j < 4; ++j) acc[i][j] = 0.f;

    int rr[8];
#pragma unroll
    for (int i = 0; i < 8; ++i)
        rr[i] = (row0 + i < nrows) ? (row0 + i) : (nrows - 1);

#pragma unroll 2
    for (int k4 = 0; k4 < FDIM; k4 += 4) {
        float4 xv[8];
#pragma unroll
        for (int i = 0; i < 8; ++i)
            xv[i] = *(const float4*)(A + (size_t)rr[i] * FDIM + k4);
#pragma unroll
        for (int q = 0; q < 4; ++q) {
            float4 wv = *(float4*)&Ws[(k4 + q) * FDIM + tx * 4];
#pragma unroll
            for (int i = 0; i < 8; ++i) {
                float xs = (q == 0) ? xv[i].x : (q == 1) ? xv[i].y : (q == 2) ? xv[i].z : xv[i].w;
                acc[i][0] = fmaf(xs, wv.x, acc[i][0]);
                acc[i][1] = fmaf(xs, wv.y, acc[i][1]);
                acc[i][2] = fmaf(xs, wv.z, acc[i][2]);
                acc[i][3] = fmaf(xs, wv.w, acc[i][3]);
            }
        }
    }
#pragma unroll
    for (int i = 0; i < 8; ++i) {
        if (row0 + i < nrows) {
            ushort4 o;
            o.x = f2bf(acc[i][0]);
            o.y = f2bf(acc[i][1]);
            o.z = f2bf(acc[i][2]);
            o.w = f2bf(acc[i][3]);
            *(ushort4*)(out + (size_t)(row0 + i) * FDIM + tx * 4) = o;
        }
    }

    float ps[8], pd[8];
#pragma unroll
    for (int i = 0; i < 8; ++i) {
        float s = 0.f, d = 0.f;
#pragma unroll
        for (int j = 0; j < 4; ++j) {
            s = fmaf(acc[i][j], sAs[tx * 4 + j], s);
            d = fmaf(acc[i][j], sAd[tx * 4 + j], d);
        }
        ps[i] = s; pd[i] = d;
    }
#pragma unroll
    for (int off = 8; off; off >>= 1) {
#pragma unroll
        for (int i = 0; i < 8; ++i) {
            ps[i] += __shfl_xor(ps[i], off);
            pd[i] += __shfl_xor(pd[i], off);
        }
    }
    if ((tx & 15) == 0) {
        int head = tx >> 4;
#pragma unroll
        for (int i = 0; i < 8; ++i) {
            if (row0 + i < nrows) {
                asrc[2 * (row0 + i) + head] = ps[i];
                adst[2 * (row0 + i) + head] = pd[i];
            }
        }
    }
}

// ---------------- per-dst softmax + aggregation: ONE WAVE PER NODE ----------------

__global__ __launch_bounds__(256) void k_aggregate(const unsigned short* __restrict__ h,
                                                   const float* __restrict__ asrc,
                                                   const float* __restrict__ adst,
                                                   const int* __restrict__ rowp,
                                                   const int* __restrict__ col,
                                                   const float* __restrict__ bias,
                                                   float* __restrict__ outbuf,
                                                   const float* __restrict__ fcW,
                                                   const float* __restrict__ fcb,
                                                   float* __restrict__ outfin, int n) {
    __shared__ int   scol[4][64];
    __shared__ float sal0[4][64], sal1[4][64];

    int t = threadIdx.x;
    int w = t >> 6;
    int lane = t & 63;
    int node = blockIdx.x * 4 + w;
    if (node >= n) return;

    int start = rowp[node];
    int deg = rowp[node + 1] - start;
    float2 adv = *(const float2*)(adst + 2 * node);
    float ad0 = adv.x, ad1 = adv.y;
    const ushort2* __restrict__ hb = (const ushort2*)h;
    const float* __restrict__ amy = (lane < 32) ? sal0[w] : sal1[w];

    float m0 = -1e30f, m1 = -1e30f;
    float p0 = 0.f, p1 = 0.f;
    float accx = 0.f, accy = 0.f;

    for (int base = 0; base < deg; base += 64) {
        int cnt = min(64, deg - base);
        float v0 = -1e30f, v1 = -1e30f;
        if (lane < cnt) {
            int s = col[start + base + lane];
            scol[w][lane] = s;
            float2 av = *(const float2*)(asrc + 2 * s);
            v0 = lrelu(av.x + ad0);
            v1 = lrelu(av.y + ad1);
        }
        float c0 = v0, c1 = v1;
#pragma unroll
        for (int off = 32; off; off >>= 1) {
            c0 = fmaxf(c0, __shfl_xor(c0, off));
            c1 = fmaxf(c1, __shfl_xor(c1, off));
        }
        float nm0 = fmaxf(m0, c0), nm1 = fmaxf(m1, c1);
        float r0 = __expf(m0 - nm0), r1 = __expf(m1 - nm1);
        m0 = nm0; m1 = nm1;
        p0 *= r0; p1 *= r1;
        float rmy = (lane < 32) ? r0 : r1;
        accx *= rmy; accy *= rmy;
        float e0 = (lane < cnt) ? __expf(v0 - m0) : 0.f;
        float e1 = (lane < cnt) ? __expf(v1 - m1) : 0.f;
        p0 += e0; p1 += e1;
        sal0[w][lane] = e0;
        sal1[w][lane] = e1;
        float2 g0 = make_float2(0.f, 0.f), g1 = make_float2(0.f, 0.f);
        float2 g2 = make_float2(0.f, 0.f), g3 = make_float2(0.f, 0.f);
        int i = 0;
        for (; i + 3 < cnt; i += 4) {
            unsigned sa = (unsigned)scol[w][i];
            unsigned sb = (unsigned)scol[w][i + 1];
            unsigned sc = (unsigned)scol[w][i + 2];
            unsigned sd = (unsigned)scol[w][i + 3];
            float wa = amy[i], wb = amy[i + 1], wc = amy[i + 2], wd = amy[i + 3];
            ushort2 ha = hb[sa * 64u + lane];
            ushort2 hv = hb[sb * 64u + lane];
            ushort2 hc = hb[sc * 64u + lane];
            ushort2 hd = hb[sd * 64u + lane];
            g0.x = fmaf(bf2f(ha.x), wa, g0.x); g0.y = fmaf(bf2f(ha.y), wa, g0.y);
            g1.x = fmaf(bf2f(hv.x), wb, g1.x); g1.y = fmaf(bf2f(hv.y), wb, g1.y);
            g2.x = fmaf(bf2f(hc.x), wc, g2.x); g2.y = fmaf(bf2f(hc.y), wc, g2.y);
            g3.x = fmaf(bf2f(hd.x), wd, g3.x); g3.y = fmaf(bf2f(hd.y), wd, g3.y);
        }
        for (; i < cnt; ++i) {
            unsigned s = (unsigned)scol[w][i];
            float a = amy[i];
            ushort2 hv = hb[s * 64u + lane];
            g0.x = fmaf(bf2f(hv.x), a, g0.x);
            g0.y = fmaf(bf2f(hv.y), a, g0.y);
        }
        accx += g0.x + g1.x + g2.x + g3.x;
        accy += g0.y + g1.y + g2.y + g3.y;
    }

#pragma unroll
    for (int off = 32; off; off >>= 1) {
        p0 += __shfl_xor(p0, off);
        p1 += __shfl_xor(p1, off);
    }
    float invmy = (lane < 32) ? 1.f / (p0 + 1e-16f) : 1.f / (p1 + 1e-16f);
    accx *= invmy;
    accy *= invmy;

    int c0i = 2 * lane, c1i = 2 * lane + 1;
    float2 bv = *(const float2*)(bias + c0i);
    float o0 = fmaxf(accx + bv.x, 0.f);
    float o1 = fmaxf(accy + bv.y, 0.f);
    if (outbuf)
        *(float2*)(outbuf + (size_t)node * FDIM + c0i) = make_float2(o0, o1);
    if (outfin) {
        float2 fv = *(const float2*)(fcW + c0i);
        float p = fmaf(o0, fv.x, o1 * fv.y);
#pragma unroll
        for (int off = 32; off; off >>= 1) p += __shfl_xor(p, off);
        if (lane == 0) outfin[node] = 1.f / (1.f + __expf(-(p + fcb[0])));
    }
}

// ---------------- host ----------------

static inline size_t rnd256(size_t x) { return (x + 255) & ~(size_t)255; }

extern "C" void kernel_launch(void* const* d_in, const int* in_sizes, int n_in,
                              void* d_out, int out_size, void* d_ws, size_t ws_size,
                              hipStream_t stream) {
    const float* x    = (const float*)d_in[0];
    const int*   ei   = (const int*)d_in[1];
    const float* W1   = (const float*)d_in[3];
    const float* as1  = (const float*)d_in[4];
    const float* ad1  = (const float*)d_in[5];
    const float* b1   = (const float*)d_in[6];
    const float* W2   = (const float*)d_in[7];
    const float* as2  = (const float*)d_in[8];
    const float* ad2  = (const float*)d_in[9];
    const float* b2   = (const float*)d_in[10];
    const float* fcW  = (const float*)d_in[11];
    const float* fcb  = (const float*)d_in[12];

    int N = in_sizes[0] / FDIM;
    int E = in_sizes[2];
    int E2 = E + N;
    const int* srcp = ei;
    const int* dstp = ei + E;

    int nb1   = (E2 + 1023) / 1024;        // radix blocks (1024 edges each)
    int nbuck = (N + 255) / 256;           // coarse buckets (256 dsts each)
    int M     = nbuck * nb1;               // hist entries

    char* w = (char*)d_ws;
    unsigned short* hbuf = (unsigned short*)w; w += rnd256((size_t)N * FDIM * sizeof(unsigned short));
    float* obuf = (float*)w;  w += rnd256((size_t)N * FDIM * sizeof(float));
    float* asrc = (float*)w;  w += rnd256((size_t)N * 2 * sizeof(float));
    float* adst = (float*)w;  w += rnd256((size_t)N * 2 * sizeof(float));
    int* rowp = (int*)w;      w += rnd256((size_t)(N + 1) * sizeof(int));
    int* bsum = (int*)w;      w += rnd256((size_t)((M + 1023) / 1024) * sizeof(int));
    int* hist = (int*)w;      w += rnd256((size_t)M * sizeof(int));
    int* part = (int*)w;      w += rnd256((size_t)E2 * sizeof(int));
    int* col  = (int*)w;      w += rnd256((size_t)E2 * sizeof(int));

    int ggrid = (N + 63) / 64;
    int agrid = (N + 3) / 4;
    int sblk  = (M + 1023) / 1024;

    // atomic-free CSR build
    k_hist<<<nb1, 256, 0, stream>>>(dstp, E, N, hist, nb1, nbuck);
    k_scan1<<<sblk, 256, 0, stream>>>(hist, hist, bsum, M);
    k_scan2<<<1, 256, 0, stream>>>(bsum, sblk);
    k_scan3<<<(M + 255) / 256, 256, 0, stream>>>(hist, bsum, M);
    k_scatter<<<nb1, 256, 0, stream>>>(srcp, dstp, E, N, hist, nb1, nbuck, part);
    k_bucket<<<nbuck, 256, 0, stream>>>(part, hist, nb1, nbuck, E2, N, rowp, col);

    // layer 1 (gemm + fused att scalars; bf16 h)
    k_gemm<<<ggrid, 256, 0, stream>>>(x, W1, hbuf, as1, ad1, asrc, adst, N);
    k_aggregate<<<agrid, 256, 0, stream>>>(hbuf, asrc, adst, rowp, col, b1,
                                           obuf, nullptr, nullptr, nullptr, N);

    // layer 2 (fc + sigmoid fused into epilogue)
    k_gemm<<<ggrid, 256, 0, stream>>>(obuf, W2, hbuf, as2, ad2, asrc, adst, N);
    k_aggregate<<<agrid, 256, 0, stream>>>(hbuf, asrc, adst, rowp, col, b2,
                                           nullptr, fcW, fcb, (float*)d_out, N);
}